// Round 12
// baseline (220.129 us; speedup 1.0000x reference)
//
#include <hip/hip_runtime.h>

typedef __bf16 bf16x8 __attribute__((ext_vector_type(8)));
typedef float  f32x4  __attribute__((ext_vector_type(4)));

#define NBAT 16
#define NP   2048
#define ND   64
#define NOUT 128
#define NK   16
#define RT   16            // rows per knn block
#define HSTR 2052          // d2 LDS row stride in halves (4104 B, 8B-aligned)

static __device__ __forceinline__ unsigned short f2bf(float f) {
    unsigned u = __float_as_uint(f);
    u += 0x7FFF + ((u >> 16) & 1);      // RNE
    return (unsigned short)(u >> 16);
}
static __device__ __forceinline__ int lanes_below(unsigned long long m) {
    return (int)__builtin_amdgcn_mbcnt_hi((unsigned)(m >> 32),
             __builtin_amdgcn_mbcnt_lo((unsigned)m, 0u));
}
static __device__ __forceinline__ unsigned long long umin64(unsigned long long a, unsigned long long b){ return a < b ? a : b; }
static __device__ __forceinline__ unsigned long long umax64(unsigned long long a, unsigned long long b){ return a < b ? b : a; }

// ascending bitonic sort of 128 u64 keys, element e = slot*64 + lane (rare path)
static __device__ __forceinline__ void bitonic_sort128_u64(unsigned long long &k0,
                                                           unsigned long long &k1, int lane) {
#pragma unroll
    for (int k = 2; k <= 64; k <<= 1) {
#pragma unroll
        for (int j = k >> 1; j >= 1; j >>= 1) {
            bool lower = ((lane & j) == 0);
            bool up0 = (k == 64) ? true  : ((lane & k) == 0);
            bool up1 = (k == 64) ? false : ((lane & k) == 0);
            unsigned long long o0 = __shfl_xor(k0, j, 64);
            k0 = (up0 == lower) ? umin64(k0, o0) : umax64(k0, o0);
            unsigned long long o1 = __shfl_xor(k1, j, 64);
            k1 = (up1 == lower) ? umin64(k1, o1) : umax64(k1, o1);
        }
    }
    { unsigned long long mn = umin64(k0, k1), mx = umax64(k0, k1); k0 = mn; k1 = mx; }
#pragma unroll
    for (int j = 32; j >= 1; j >>= 1) {
        bool lower = ((lane & j) == 0);
        unsigned long long o0 = __shfl_xor(k0, j, 64);
        k0 = lower ? umin64(k0, o0) : umax64(k0, o0);
        unsigned long long o1 = __shfl_xor(k1, j, 64);
        k1 = lower ? umin64(k1, o1) : umax64(k1, o1);
    }
}

// fp64-exact squared distance, rounded to fp32 (single row)
static __device__ __forceinline__ float
refine_d(const float* __restrict__ x, int gr, int gcbase, int jc) {
    const float* xr = x + (size_t)gr * ND;
    const float* xc = x + (size_t)(gcbase + jc) * ND;
    double s0 = 0.0, s1 = 0.0;
#pragma unroll
    for (int k8 = 0; k8 < 8; ++k8) {
        float4 a  = *(const float4*)(xr + k8 * 8);
        float4 b  = *(const float4*)(xc + k8 * 8);
        float4 a2 = *(const float4*)(xr + k8 * 8 + 4);
        float4 b2 = *(const float4*)(xc + k8 * 8 + 4);
        double e0 = (double)a.x - (double)b.x;
        double e1 = (double)a.y - (double)b.y;
        double e2 = (double)a.z - (double)b.z;
        double e3 = (double)a.w - (double)b.w;
        s0 = fma(e0, e0, s0); s0 = fma(e1, e1, s0);
        s0 = fma(e2, e2, s0); s0 = fma(e3, e3, s0);
        double f0 = (double)a2.x - (double)b2.x;
        double f1 = (double)a2.y - (double)b2.y;
        double f2 = (double)a2.z - (double)b2.z;
        double f3 = (double)a2.w - (double)b2.w;
        s1 = fma(f0, f0, s1); s1 = fma(f1, f1, s1);
        s1 = fma(f2, f2, s1); s1 = fma(f3, f3, s1);
    }
    return (float)(s0 + s1);
}

// split fp32 x8 -> hi/lo bf16x8 (hi = RNE(f); lo = RNE(f - hi))
static __device__ __forceinline__ void cvt_hilo(const float* __restrict__ p,
                                                bf16x8 &hi, bf16x8 &lo) {
    float4 a = *(const float4*)p, b = *(const float4*)(p + 4);
    float f[8] = {a.x, a.y, a.z, a.w, b.x, b.y, b.z, b.w};
#pragma unroll
    for (int i = 0; i < 8; ++i) {
        __bf16 h = (__bf16)f[i];
        hi[i] = h;
        lo[i] = (__bf16)(f[i] - (float)h);
    }
}

// ---------------------------------------------------------------------------
// prep (LDS-free, MFMA): sq (fp64-acc), xb16 (bf16 copy), U=(W1-W2)x+b, V=W2x.
// grid 512 x 256; each block 4 row-tiles of 16; W frags hoisted across tiles.
// ---------------------------------------------------------------------------
__global__ void __launch_bounds__(256)
prep_k(const float* __restrict__ x,     // [32768][64]
       const float* __restrict__ W,     // [128][128] (cols 0..63 = W1, 64..127 = W2)
       const float* __restrict__ bias,  // [128]
       float* __restrict__ sq, float* __restrict__ U,
       float* __restrict__ V,  unsigned short* __restrict__ xb16)
{
    const int blk = blockIdx.x, tid = threadIdx.x;
    const int R0b = blk * 64;
    const int w  = tid >> 6, l = tid & 63;
    const int l15 = l & 15, lg = l >> 4, kc = lg * 8;

    bf16x8 wh[2][4], wl[2][4];
#pragma unroll
    for (int tt = 0; tt < 2; ++tt) {
        const float* wb = W + (size_t)((w + tt * 4) * 16 + l15) * (2 * ND) + kc;
#pragma unroll
        for (int p = 0; p < 4; ++p)
            cvt_hilo(wb + p * 32, wh[tt][p], wl[tt][p]);
    }
    const int o0a = w * 16 + lg * 4;
    const int o0b = (w + 4) * 16 + lg * 4;
    float4 boa = *(const float4*)(bias + o0a);
    float4 bob = *(const float4*)(bias + o0b);

#pragma unroll 1
    for (int s4 = 0; s4 < 4; ++s4) {
        const int R0 = R0b + s4 * 16;
        {
            int r = tid >> 4, c = (tid & 15) * 4;
            float4 v = *(const float4*)(x + (size_t)(R0 + r) * ND + c);
            ushort4 hb;
            hb.x = f2bf(v.x); hb.y = f2bf(v.y); hb.z = f2bf(v.z); hb.w = f2bf(v.w);
            *(ushort4*)(xb16 + (size_t)(R0 + r) * ND + c) = hb;
        }
        if (tid < 128) {
            int r = tid >> 3, seg = tid & 7;
            const float* p = x + (size_t)(R0 + r) * ND + seg * 8;
            float4 a = *(const float4*)(p);
            float4 b = *(const float4*)(p + 4);
            double s = (double)a.x * a.x + (double)a.y * a.y +
                       (double)a.z * a.z + (double)a.w * a.w +
                       (double)b.x * b.x + (double)b.y * b.y +
                       (double)b.z * b.z + (double)b.w * b.w;
            s += __shfl_xor(s, 1, 64);
            s += __shfl_xor(s, 2, 64);
            s += __shfl_xor(s, 4, 64);
            if (seg == 0) sq[R0 + r] = (float)s;
        }
        const float* xr = x + (size_t)(R0 + l15) * ND + kc;
        bf16x8 bh0, bl0, bh1, bl1;
        cvt_hilo(xr,      bh0, bl0);
        cvt_hilo(xr + 32, bh1, bl1);
#pragma unroll
        for (int tt = 0; tt < 2; ++tt) {
            f32x4 accP = {0.f, 0.f, 0.f, 0.f};
            f32x4 accV = {0.f, 0.f, 0.f, 0.f};
            accP = __builtin_amdgcn_mfma_f32_16x16x32_bf16(wh[tt][0], bh0, accP, 0, 0, 0);
            accP = __builtin_amdgcn_mfma_f32_16x16x32_bf16(wh[tt][0], bl0, accP, 0, 0, 0);
            accP = __builtin_amdgcn_mfma_f32_16x16x32_bf16(wl[tt][0], bh0, accP, 0, 0, 0);
            accP = __builtin_amdgcn_mfma_f32_16x16x32_bf16(wh[tt][1], bh1, accP, 0, 0, 0);
            accP = __builtin_amdgcn_mfma_f32_16x16x32_bf16(wh[tt][1], bl1, accP, 0, 0, 0);
            accP = __builtin_amdgcn_mfma_f32_16x16x32_bf16(wl[tt][1], bh1, accP, 0, 0, 0);
            accV = __builtin_amdgcn_mfma_f32_16x16x32_bf16(wh[tt][2], bh0, accV, 0, 0, 0);
            accV = __builtin_amdgcn_mfma_f32_16x16x32_bf16(wh[tt][2], bl0, accV, 0, 0, 0);
            accV = __builtin_amdgcn_mfma_f32_16x16x32_bf16(wl[tt][2], bh0, accV, 0, 0, 0);
            accV = __builtin_amdgcn_mfma_f32_16x16x32_bf16(wh[tt][3], bh1, accV, 0, 0, 0);
            accV = __builtin_amdgcn_mfma_f32_16x16x32_bf16(wh[tt][3], bl1, accV, 0, 0, 0);
            accV = __builtin_amdgcn_mfma_f32_16x16x32_bf16(wl[tt][3], bh1, accV, 0, 0, 0);
            const int o0 = tt ? o0b : o0a;
            float4 bo = tt ? bob : boa;
            float4 uu, vv;
            uu.x = accP[0] - accV[0] + bo.x;  vv.x = accV[0];
            uu.y = accP[1] - accV[1] + bo.y;  vv.y = accV[1];
            uu.z = accP[2] - accV[2] + bo.z;  vv.z = accV[2];
            uu.w = accP[3] - accV[3] + bo.w;  vv.w = accV[3];
            *(float4*)(U + (size_t)(R0 + l15) * NOUT + o0) = uu;
            *(float4*)(V + (size_t)(R0 + l15) * NOUT + o0) = vv;
        }
    }
}

// ---------------------------------------------------------------------------
// knn + aggregate. grid 2048 x 512 (8 waves), RT=16, 2 blocks/CU.
// Phase 1: bf16 MFMA Gram -> fp16 d2 tile (66 KB LDS), 16 col-tiles/wave.
// Phase 2: each wave TWO rows (w, w+8) INTERLEAVED (ILP hides the serial
// ballot-radix round-trips): tau via 10-rd radix on fp16>>6 (+granule +1.0
// widen); scan compaction; divergence-free fp64 refine; 31-rd T radix
// (interleaved); exact-16 winner mask; 16 in-flight V loads per row.
// sort128_u64 fallback (>64 survivors or ambiguous fp32 tie).
// ---------------------------------------------------------------------------
__global__ void __launch_bounds__(512, 2)
knn_k(const float* __restrict__ x,             // [32768][64] fp32 (refine)
      const unsigned short* __restrict__ xb16, // [32768][64] bf16
      const float* __restrict__ sq,
      const float* __restrict__ U,
      const float* __restrict__ V,
      float* __restrict__ out)
{
    extern __shared__ __align__(16) unsigned char smem[];
    unsigned short* d2h = (unsigned short*)smem;   // [RT][HSTR] halves
    __shared__ unsigned short cbuf[8][2][128];

    // XCD-aware decode: q%8 = XCD; each XCD gets 2 full batches
    const int q   = blockIdx.x;
    const int xcd = q & 7;
    const int k_  = q >> 3;               // 0..255
    const int bb  = xcd * 2 + (k_ >> 7);  // batch
    const int rt  = k_ & 127;             // row tile within batch
    const int R0l = rt * RT;
    const int R0g = bb * NP + R0l;
    const int tid = threadIdx.x;
    const int w   = tid >> 6;             // 0..7
    const int l   = tid & 63;
    const int l15 = l & 15, lg = l >> 4, kc = lg * 8;

    const unsigned short* nr = xb16 + (size_t)(R0g + l15) * ND + kc;
    bf16x8 n0 = *(const bf16x8*)(nr);
    bf16x8 n1 = *(const bf16x8*)(nr + 32);
    const float sqrow = sq[R0g + l15];

    const unsigned short* xbb = xb16 + (size_t)bb * NP * ND;
    const float* sqb = sq + bb * NP;

    // ---- Phase 1: MFMA Gram -> fp16 d2 in LDS (16 col-tiles per wave) ----
#pragma unroll 4
    for (int t = 0; t < 16; ++t) {
        const int cb = (w * 16 + t) * 16;
        const unsigned short* ar = xbb + (size_t)(cb + l15) * ND + kc;
        bf16x8 a0 = *(const bf16x8*)(ar);
        bf16x8 a1 = *(const bf16x8*)(ar + 32);
        f32x4 acc = {0.f, 0.f, 0.f, 0.f};
        acc = __builtin_amdgcn_mfma_f32_16x16x32_bf16(a0, n0, acc, 0, 0, 0);
        acc = __builtin_amdgcn_mfma_f32_16x16x32_bf16(a1, n1, acc, 0, 0, 0);
        const int jb4 = cb + lg * 4;
        float4 sq4 = *(const float4*)(sqb + jb4);
        unsigned short hh[4];
#pragma unroll
        for (int i = 0; i < 4; ++i) {
            float sqc = (i == 0) ? sq4.x : (i == 1) ? sq4.y : (i == 2) ? sq4.z : sq4.w;
            float d2 = fmaxf(fmaf(-2.f, acc[i], sqrow + sqc), 0.f);
            unsigned short h = __builtin_bit_cast(unsigned short, (_Float16)d2);
            if (R0l + l15 == jb4 + i) h = 0x7C00;   // self -> +inf
            hh[i] = h;
        }
        ushort4 hv; hv.x = hh[0]; hv.y = hh[1]; hv.z = hh[2]; hv.w = hh[3];
        *(ushort4*)(d2h + (size_t)l15 * HSTR + jb4) = hv;
    }
    __syncthreads();

    // ---- Phase 2: TWO rows per wave, interleaved ----
    const int gcbase = bb * NP;
    const int rA = w, rB = w + 8;
    const int grA = R0g + rA, grB = R0g + rB;
    const unsigned short* rpA = d2h + (size_t)rA * HSTR;
    const unsigned short* rpB = d2h + (size_t)rB * HSTR;

    unsigned int hA[32], hB[32];
#pragma unroll
    for (int s = 0; s < 8; ++s) {
        ushort4 a = *(const ushort4*)(rpA + (s * 64 + l) * 4);
        ushort4 b = *(const ushort4*)(rpB + (s * 64 + l) * 4);
        hA[s*4+0] = a.x; hA[s*4+1] = a.y; hA[s*4+2] = a.z; hA[s*4+3] = a.w;
        hB[s*4+0] = b.x; hB[s*4+1] = b.y; hB[s*4+2] = b.z; hB[s*4+3] = b.w;
    }
    unsigned int mnA = hA[0], mnB = hB[0];
#pragma unroll
    for (int i = 1; i < 32; ++i) {
        mnA = (hA[i] < mnA) ? hA[i] : mnA;
        mnB = (hB[i] < mnB) ? hB[i] : mnB;
    }

    // tau: 10-round radix on fp16>>6, interleaved (granule-inclusive)
    unsigned int m6A = mnA >> 6, m6B = mnB >> 6;
    unsigned int tA = 0, tB = 0;
#pragma unroll
    for (int b = 9; b >= 0; --b) {
        unsigned int cA = tA | (1u << b);
        unsigned int cB = tB | (1u << b);
        int nA = __popcll(__ballot(m6A < cA));
        int nB = __popcll(__ballot(m6B < cB));
        if (nA < 16) tA = cA;
        if (nB < 16) tB = cB;
    }
    // widen: include whole granule, +1.0 absolute (bf16 Gram noise), +1 ulp
    float tfA = (float)__builtin_bit_cast(_Float16, (unsigned short)((tA << 6) | 0x3F)) + 1.0f;
    float tfB = (float)__builtin_bit_cast(_Float16, (unsigned short)((tB << 6) | 0x3F)) + 1.0f;
    unsigned int tauA = (unsigned int)__builtin_bit_cast(unsigned short, (_Float16)tfA) + 1u;
    unsigned int tauB = (unsigned int)__builtin_bit_cast(unsigned short, (_Float16)tfB) + 1u;

    // per-lane survivor pack (slot ids, 5 bits each, up to 4)
    unsigned int pkA = 0, pkB = 0; int cntA = 0, cntB = 0;
#pragma unroll
    for (int i = 0; i < 32; ++i) {
        if (hA[i] <= tauA) { if (cntA < 4) pkA |= (unsigned)i << (5 * cntA); ++cntA; }
        if (hB[i] <= tauB) { if (cntB < 4) pkB |= (unsigned)i << (5 * cntB); ++cntB; }
    }
    bool ovfA = (__ballot(cntA > 4) != 0ull);
    bool ovfB = (__ballot(cntB > 4) != 0ull);

    cbuf[w][0][l] = 0xFFFF; cbuf[w][0][64 + l] = 0xFFFF;
    cbuf[w][1][l] = 0xFFFF; cbuf[w][1][64 + l] = 0xFFFF;
    int totA, totB;
    {
        // interleaved exclusive scans
        int iA = cntA, iB = cntB;
#pragma unroll
        for (int off = 1; off < 64; off <<= 1) {
            int uA = __shfl_up(iA, off, 64);
            int uB = __shfl_up(iB, off, 64);
            if (l >= off) { iA += uA; iB += uB; }
        }
        int exA = iA - cntA, exB = iB - cntB;
        totA = __shfl(iA, 63, 64);
        totB = __shfl(iB, 63, 64);
        if (!ovfA) {
#pragma unroll
            for (int kk = 0; kk < 4; ++kk)
                if (kk < cntA && exA + kk < 128) {
                    int s = (pkA >> (5 * kk)) & 31;
                    cbuf[w][0][exA + kk] = (unsigned short)(256 * (s >> 2) + 4 * l + (s & 3));
                }
        } else {
            int base = 0;
#pragma unroll 1
            for (int i = 0; i < 32; ++i) {
                bool p = (hA[i] <= tauA);
                unsigned long long m = __ballot(p);
                int pos = base + lanes_below(m);
                if (p && pos < 128)
                    cbuf[w][0][pos] = (unsigned short)(256 * (i >> 2) + 4 * l + (i & 3));
                base += __popcll(m);
            }
            totA = base;
        }
        if (!ovfB) {
#pragma unroll
            for (int kk = 0; kk < 4; ++kk)
                if (kk < cntB && exB + kk < 128) {
                    int s = (pkB >> (5 * kk)) & 31;
                    cbuf[w][1][exB + kk] = (unsigned short)(256 * (s >> 2) + 4 * l + (s & 3));
                }
        } else {
            int base = 0;
#pragma unroll 1
            for (int i = 0; i < 32; ++i) {
                bool p = (hB[i] <= tauB);
                unsigned long long m = __ballot(p);
                int pos = base + lanes_below(m);
                if (p && pos < 128)
                    cbuf[w][1][pos] = (unsigned short)(256 * (i >> 2) + 4 * l + (i & 3));
                base += __popcll(m);
            }
            totB = base;
        }
    }
    asm volatile("s_waitcnt lgkmcnt(0)" ::: "memory");
    __builtin_amdgcn_sched_barrier(0);

    const float* Vb = V + (size_t)bb * NP * NOUT;
    int jcA = cbuf[w][0][l];
    int jcB = cbuf[w][1][l];

    // divergence-free fp64 refine, both rows (4 independent FMA chains)
    int jsA = (jcA == 0xFFFF) ? 0 : jcA;
    int jsB = (jcB == 0xFFFF) ? 0 : jcB;
    unsigned int dbA, dbB;
    {
        const float* xrA = x + (size_t)grA * ND;
        const float* xcA = x + (size_t)(gcbase + jsA) * ND;
        const float* xrB = x + (size_t)grB * ND;
        const float* xcB = x + (size_t)(gcbase + jsB) * ND;
        double a0 = 0.0, a1 = 0.0, b0 = 0.0, b1 = 0.0;
#pragma unroll
        for (int k8 = 0; k8 < 8; ++k8) {
            float4 ra  = *(const float4*)(xrA + k8 * 8);
            float4 ca  = *(const float4*)(xcA + k8 * 8);
            float4 ra2 = *(const float4*)(xrA + k8 * 8 + 4);
            float4 ca2 = *(const float4*)(xcA + k8 * 8 + 4);
            float4 rb  = *(const float4*)(xrB + k8 * 8);
            float4 cb2 = *(const float4*)(xcB + k8 * 8);
            float4 rb2 = *(const float4*)(xrB + k8 * 8 + 4);
            float4 cb3 = *(const float4*)(xcB + k8 * 8 + 4);
            double e0 = (double)ra.x - (double)ca.x;
            double e1 = (double)ra.y - (double)ca.y;
            double e2 = (double)ra.z - (double)ca.z;
            double e3 = (double)ra.w - (double)ca.w;
            a0 = fma(e0, e0, a0); a0 = fma(e1, e1, a0);
            a0 = fma(e2, e2, a0); a0 = fma(e3, e3, a0);
            double f0 = (double)ra2.x - (double)ca2.x;
            double f1 = (double)ra2.y - (double)ca2.y;
            double f2 = (double)ra2.z - (double)ca2.z;
            double f3 = (double)ra2.w - (double)ca2.w;
            a1 = fma(f0, f0, a1); a1 = fma(f1, f1, a1);
            a1 = fma(f2, f2, a1); a1 = fma(f3, f3, a1);
            double g0 = (double)rb.x - (double)cb2.x;
            double g1 = (double)rb.y - (double)cb2.y;
            double g2 = (double)rb.z - (double)cb2.z;
            double g3 = (double)rb.w - (double)cb2.w;
            b0 = fma(g0, g0, b0); b0 = fma(g1, g1, b0);
            b0 = fma(g2, g2, b0); b0 = fma(g3, g3, b0);
            double h0 = (double)rb2.x - (double)cb3.x;
            double h1 = (double)rb2.y - (double)cb3.y;
            double h2 = (double)rb2.z - (double)cb3.z;
            double h3 = (double)rb2.w - (double)cb3.w;
            b1 = fma(h0, h0, b1); b1 = fma(h1, h1, b1);
            b1 = fma(h2, h2, b1); b1 = fma(h3, h3, b1);
        }
        dbA = (jcA == 0xFFFF) ? 0xFFFFFFFFu : __float_as_uint((float)(a0 + a1));
        dbB = (jcB == 0xFFFF) ? 0xFFFFFFFFu : __float_as_uint((float)(b0 + b1));
    }

    // T radix (31 rounds), interleaved
    unsigned int TA = 0, TB = 0;
#pragma unroll
    for (int b = 30; b >= 0; --b) {
        unsigned int cA = TA | (1u << b);
        unsigned int cB = TB | (1u << b);
        int nA = __popcll(__ballot(dbA < cA));
        int nB = __popcll(__ballot(dbB < cB));
        if (nA < 16) TA = cA;
        if (nB < 16) TB = cB;
    }
    unsigned long long lessA = __ballot(dbA < TA);
    unsigned long long lessB = __ballot(dbB < TB);
    int needA = 16 - __popcll(lessA);
    int needB = 16 - __popcll(lessB);
    unsigned long long tieA = __ballot(dbA == TA);
    unsigned long long tieB = __ballot(dbB == TB);
    bool fastA = (totA <= 64) && (__popcll(tieA) == needA);
    bool fastB = (totB <= 64) && (__popcll(tieB) == needB);

    float mvA0 = -1e30f, mvA1 = -1e30f, mvB0 = -1e30f, mvB1 = -1e30f;

    if (fastA && fastB) {
        unsigned long long wmA = lessA | tieA;
        unsigned long long wmB = lessB | tieB;
        int jnA[NK], jnB[NK];
#pragma unroll
        for (int n = 0; n < NK; ++n) {
            int lnA = __ffsll((long long)wmA) - 1; wmA &= wmA - 1;
            int lnB = __ffsll((long long)wmB) - 1; wmB &= wmB - 1;
            jnA[n] = __builtin_amdgcn_readlane(jcA, lnA);
            jnB[n] = __builtin_amdgcn_readlane(jcB, lnB);
        }
        float2 vA[NK], vB[NK];
#pragma unroll
        for (int n = 0; n < NK; ++n) {
            vA[n] = *(const float2*)(Vb + (size_t)jnA[n] * NOUT + (l << 1));
            vB[n] = *(const float2*)(Vb + (size_t)jnB[n] * NOUT + (l << 1));
        }
#pragma unroll
        for (int n = 0; n < NK; ++n) {
            mvA0 = fmaxf(mvA0, vA[n].x); mvA1 = fmaxf(mvA1, vA[n].y);
            mvB0 = fmaxf(mvB0, vB[n].x); mvB1 = fmaxf(mvB1, vB[n].y);
        }
    } else {
        // rare: handle each row independently (fast or exact-sort fallback)
#pragma unroll 1
        for (int half = 0; half < 2; ++half) {
            bool fa  = half ? fastB : fastA;
            int  jc  = half ? jcB : jcA;
            int  gr  = half ? grB : grA;
            int  tot = half ? totB : totA;
            unsigned long long wm = half ? (lessB | tieB) : (lessA | tieA);
            float m0 = -1e30f, m1 = -1e30f;
            if (fa) {
                int jns[NK];
                unsigned long long mm = wm;
#pragma unroll
                for (int n = 0; n < NK; ++n) {
                    int ln = __ffsll((long long)mm) - 1; mm &= mm - 1;
                    jns[n] = __builtin_amdgcn_readlane(jc, ln);
                }
                float2 vv[NK];
#pragma unroll
                for (int n = 0; n < NK; ++n)
                    vv[n] = *(const float2*)(Vb + (size_t)jns[n] * NOUT + (l << 1));
#pragma unroll
                for (int n = 0; n < NK; ++n) {
                    m0 = fmaxf(m0, vv[n].x); m1 = fmaxf(m1, vv[n].y);
                }
            } else {
                int jc1 = cbuf[w][half][64 + l];
                unsigned long long rk0 = (jc != 0xFFFF)
                    ? ((((unsigned long long)__float_as_uint(refine_d(x, gr, gcbase, jc))) << 11) | (unsigned)jc)
                    : ~0ull;
                unsigned long long rk1 = (jc1 != 0xFFFF)
                    ? ((((unsigned long long)__float_as_uint(refine_d(x, gr, gcbase, jc1))) << 11) | (unsigned)jc1)
                    : ~0ull;
                bitonic_sort128_u64(rk0, rk1, l);
                int nbr = (int)(rk0 & 2047u);
                int jns[NK];
#pragma unroll
                for (int n = 0; n < NK; ++n)
                    jns[n] = __builtin_amdgcn_readlane(nbr, n);
                float2 vv[NK];
#pragma unroll
                for (int n = 0; n < NK; ++n)
                    vv[n] = *(const float2*)(Vb + (size_t)jns[n] * NOUT + (l << 1));
#pragma unroll
                for (int n = 0; n < NK; ++n) {
                    m0 = fmaxf(m0, vv[n].x); m1 = fmaxf(m1, vv[n].y);
                }
            }
            if (half) { mvB0 = m0; mvB1 = m1; } else { mvA0 = m0; mvA1 = m1; }
        }
    }

    float2 uA = *(const float2*)(U + (size_t)grA * NOUT + (l << 1));
    float2 uB = *(const float2*)(U + (size_t)grB * NOUT + (l << 1));
    float2 oA, oB;
    oA.x = fmaxf(uA.x + mvA0, 0.f);
    oA.y = fmaxf(uA.y + mvA1, 0.f);
    oB.x = fmaxf(uB.x + mvB0, 0.f);
    oB.y = fmaxf(uB.y + mvB1, 0.f);
    *(float2*)(out + (size_t)grA * NOUT + (l << 1)) = oA;
    *(float2*)(out + (size_t)grB * NOUT + (l << 1)) = oB;
}

extern "C" void kernel_launch(void* const* d_in, const int* in_sizes, int n_in,
                              void* d_out, int out_size, void* d_ws, size_t ws_size,
                              hipStream_t stream) {
    const float* x    = (const float*)d_in[0];   // fp32 [32768][64]
    // d_in[1] = pos (unused), d_in[2] = batch (unused; uniform sorted segments)
    const float* W    = (const float*)d_in[3];   // fp32 [128][128]
    const float* bias = (const float*)d_in[4];   // fp32 [128]
    float* out = (float*)d_out;                  // fp32 [32768][128]

    float* sq = (float*)d_ws;                               // 32768 f32
    float* U  = sq + NBAT * NP;                             // 4.19M f32
    float* V  = U  + (size_t)NBAT * NP * NOUT;              // 4.19M f32
    unsigned short* xb16 = (unsigned short*)(V + (size_t)NBAT * NP * NOUT);

    prep_k<<<512, 256, 0, stream>>>(x, W, bias, sq, U, V, xb16);

    const int lds_bytes = RT * HSTR * 2;                    // 65,664 B
    (void)hipFuncSetAttribute((const void*)knn_k,
                        hipFuncAttributeMaxDynamicSharedMemorySize, lds_bytes);
    knn_k<<<2048, 512, lds_bytes, stream>>>(x, xb16, sq, U, V, out);
}

// Round 14
// 165.459 us; speedup vs baseline: 1.3304x; 1.3304x over previous
//
#include <hip/hip_runtime.h>

typedef __bf16 bf16x8 __attribute__((ext_vector_type(8)));
typedef float  f32x4  __attribute__((ext_vector_type(4)));

#define NBAT 16
#define NP   2048
#define ND   64
#define NOUT 128
#define NK   16
#define RT   16            // rows per knn block
#define HSTR 2052          // d2 LDS row stride in halves (4104 B, 8B-aligned)

static __device__ __forceinline__ unsigned short f2bf(float f) {
    unsigned u = __float_as_uint(f);
    u += 0x7FFF + ((u >> 16) & 1);      // RNE
    return (unsigned short)(u >> 16);
}
static __device__ __forceinline__ int lanes_below(unsigned long long m) {
    return (int)__builtin_amdgcn_mbcnt_hi((unsigned)(m >> 32),
             __builtin_amdgcn_mbcnt_lo((unsigned)m, 0u));
}
static __device__ __forceinline__ unsigned long long umin64(unsigned long long a, unsigned long long b){ return a < b ? a : b; }
static __device__ __forceinline__ unsigned long long umax64(unsigned long long a, unsigned long long b){ return a < b ? b : a; }

// ascending bitonic sort of 128 u64 keys, element e = slot*64 + lane (rare path)
static __device__ __forceinline__ void bitonic_sort128_u64(unsigned long long &k0,
                                                           unsigned long long &k1, int lane) {
#pragma unroll
    for (int k = 2; k <= 64; k <<= 1) {
#pragma unroll
        for (int j = k >> 1; j >= 1; j >>= 1) {
            bool lower = ((lane & j) == 0);
            bool up0 = (k == 64) ? true  : ((lane & k) == 0);
            bool up1 = (k == 64) ? false : ((lane & k) == 0);
            unsigned long long o0 = __shfl_xor(k0, j, 64);
            k0 = (up0 == lower) ? umin64(k0, o0) : umax64(k0, o0);
            unsigned long long o1 = __shfl_xor(k1, j, 64);
            k1 = (up1 == lower) ? umin64(k1, o1) : umax64(k1, o1);
        }
    }
    { unsigned long long mn = umin64(k0, k1), mx = umax64(k0, k1); k0 = mn; k1 = mx; }
#pragma unroll
    for (int j = 32; j >= 1; j >>= 1) {
        bool lower = ((lane & j) == 0);
        unsigned long long o0 = __shfl_xor(k0, j, 64);
        k0 = lower ? umin64(k0, o0) : umax64(k0, o0);
        unsigned long long o1 = __shfl_xor(k1, j, 64);
        k1 = lower ? umin64(k1, o1) : umax64(k1, o1);
    }
}

// fp64-exact squared distance, rounded to fp32 (4 independent accumulators)
static __device__ __forceinline__ float
refine_d(const float* __restrict__ x, int gr, int gcbase, int jc) {
    const float* xr = x + (size_t)gr * ND;
    const float* xc = x + (size_t)(gcbase + jc) * ND;
    double s0 = 0.0, s1 = 0.0, s2 = 0.0, s3 = 0.0;
#pragma unroll
    for (int k16 = 0; k16 < 4; ++k16) {
        const float* pr = xr + k16 * 16;
        const float* pc = xc + k16 * 16;
        float4 a0 = *(const float4*)(pr);
        float4 b0 = *(const float4*)(pc);
        float4 a1 = *(const float4*)(pr + 4);
        float4 b1 = *(const float4*)(pc + 4);
        float4 a2 = *(const float4*)(pr + 8);
        float4 b2 = *(const float4*)(pc + 8);
        float4 a3 = *(const float4*)(pr + 12);
        float4 b3 = *(const float4*)(pc + 12);
        double e0 = (double)a0.x - (double)b0.x;
        double e1 = (double)a0.y - (double)b0.y;
        double e2 = (double)a0.z - (double)b0.z;
        double e3 = (double)a0.w - (double)b0.w;
        s0 = fma(e0, e0, s0); s0 = fma(e1, e1, s0);
        s0 = fma(e2, e2, s0); s0 = fma(e3, e3, s0);
        double f0 = (double)a1.x - (double)b1.x;
        double f1 = (double)a1.y - (double)b1.y;
        double f2 = (double)a1.z - (double)b1.z;
        double f3 = (double)a1.w - (double)b1.w;
        s1 = fma(f0, f0, s1); s1 = fma(f1, f1, s1);
        s1 = fma(f2, f2, s1); s1 = fma(f3, f3, s1);
        double g0 = (double)a2.x - (double)b2.x;
        double g1 = (double)a2.y - (double)b2.y;
        double g2 = (double)a2.z - (double)b2.z;
        double g3 = (double)a2.w - (double)b2.w;
        s2 = fma(g0, g0, s2); s2 = fma(g1, g1, s2);
        s2 = fma(g2, g2, s2); s2 = fma(g3, g3, s2);
        double h0 = (double)a3.x - (double)b3.x;
        double h1 = (double)a3.y - (double)b3.y;
        double h2 = (double)a3.z - (double)b3.z;
        double h3 = (double)a3.w - (double)b3.w;
        s3 = fma(h0, h0, s3); s3 = fma(h1, h1, s3);
        s3 = fma(h2, h2, s3); s3 = fma(h3, h3, s3);
    }
    return (float)((s0 + s1) + (s2 + s3));
}

// split fp32 x8 -> hi/lo bf16x8 (hi = RNE(f); lo = RNE(f - hi))
static __device__ __forceinline__ void cvt_hilo(const float* __restrict__ p,
                                                bf16x8 &hi, bf16x8 &lo) {
    float4 a = *(const float4*)p, b = *(const float4*)(p + 4);
    float f[8] = {a.x, a.y, a.z, a.w, b.x, b.y, b.z, b.w};
#pragma unroll
    for (int i = 0; i < 8; ++i) {
        __bf16 h = (__bf16)f[i];
        hi[i] = h;
        lo[i] = (__bf16)(f[i] - (float)h);
    }
}

// ---------------------------------------------------------------------------
// prep (LDS-free, MFMA): sq (fp64-acc), xb16 (bf16 copy), U=(W1-W2)x+b, V=W2x.
// grid 512 x 256; each block 4 row-tiles of 16; W frags hoisted across tiles.
// ---------------------------------------------------------------------------
__global__ void __launch_bounds__(256)
prep_k(const float* __restrict__ x,     // [32768][64]
       const float* __restrict__ W,     // [128][128] (cols 0..63 = W1, 64..127 = W2)
       const float* __restrict__ bias,  // [128]
       float* __restrict__ sq, float* __restrict__ U,
       float* __restrict__ V,  unsigned short* __restrict__ xb16)
{
    const int blk = blockIdx.x, tid = threadIdx.x;
    const int R0b = blk * 64;
    const int w  = tid >> 6, l = tid & 63;
    const int l15 = l & 15, lg = l >> 4, kc = lg * 8;

    bf16x8 wh[2][4], wl[2][4];
#pragma unroll
    for (int tt = 0; tt < 2; ++tt) {
        const float* wb = W + (size_t)((w + tt * 4) * 16 + l15) * (2 * ND) + kc;
#pragma unroll
        for (int p = 0; p < 4; ++p)
            cvt_hilo(wb + p * 32, wh[tt][p], wl[tt][p]);
    }
    const int o0a = w * 16 + lg * 4;
    const int o0b = (w + 4) * 16 + lg * 4;
    float4 boa = *(const float4*)(bias + o0a);
    float4 bob = *(const float4*)(bias + o0b);

#pragma unroll 1
    for (int s4 = 0; s4 < 4; ++s4) {
        const int R0 = R0b + s4 * 16;
        {
            int r = tid >> 4, c = (tid & 15) * 4;
            float4 v = *(const float4*)(x + (size_t)(R0 + r) * ND + c);
            ushort4 hb;
            hb.x = f2bf(v.x); hb.y = f2bf(v.y); hb.z = f2bf(v.z); hb.w = f2bf(v.w);
            *(ushort4*)(xb16 + (size_t)(R0 + r) * ND + c) = hb;
        }
        if (tid < 128) {
            int r = tid >> 3, seg = tid & 7;
            const float* p = x + (size_t)(R0 + r) * ND + seg * 8;
            float4 a = *(const float4*)(p);
            float4 b = *(const float4*)(p + 4);
            double s = (double)a.x * a.x + (double)a.y * a.y +
                       (double)a.z * a.z + (double)a.w * a.w +
                       (double)b.x * b.x + (double)b.y * b.y +
                       (double)b.z * b.z + (double)b.w * b.w;
            s += __shfl_xor(s, 1, 64);
            s += __shfl_xor(s, 2, 64);
            s += __shfl_xor(s, 4, 64);
            if (seg == 0) sq[R0 + r] = (float)s;
        }
        const float* xr = x + (size_t)(R0 + l15) * ND + kc;
        bf16x8 bh0, bl0, bh1, bl1;
        cvt_hilo(xr,      bh0, bl0);
        cvt_hilo(xr + 32, bh1, bl1);
#pragma unroll
        for (int tt = 0; tt < 2; ++tt) {
            f32x4 accP = {0.f, 0.f, 0.f, 0.f};
            f32x4 accV = {0.f, 0.f, 0.f, 0.f};
            accP = __builtin_amdgcn_mfma_f32_16x16x32_bf16(wh[tt][0], bh0, accP, 0, 0, 0);
            accP = __builtin_amdgcn_mfma_f32_16x16x32_bf16(wh[tt][0], bl0, accP, 0, 0, 0);
            accP = __builtin_amdgcn_mfma_f32_16x16x32_bf16(wl[tt][0], bh0, accP, 0, 0, 0);
            accP = __builtin_amdgcn_mfma_f32_16x16x32_bf16(wh[tt][1], bh1, accP, 0, 0, 0);
            accP = __builtin_amdgcn_mfma_f32_16x16x32_bf16(wh[tt][1], bl1, accP, 0, 0, 0);
            accP = __builtin_amdgcn_mfma_f32_16x16x32_bf16(wl[tt][1], bh1, accP, 0, 0, 0);
            accV = __builtin_amdgcn_mfma_f32_16x16x32_bf16(wh[tt][2], bh0, accV, 0, 0, 0);
            accV = __builtin_amdgcn_mfma_f32_16x16x32_bf16(wh[tt][2], bl0, accV, 0, 0, 0);
            accV = __builtin_amdgcn_mfma_f32_16x16x32_bf16(wl[tt][2], bh0, accV, 0, 0, 0);
            accV = __builtin_amdgcn_mfma_f32_16x16x32_bf16(wh[tt][3], bh1, accV, 0, 0, 0);
            accV = __builtin_amdgcn_mfma_f32_16x16x32_bf16(wh[tt][3], bl1, accV, 0, 0, 0);
            accV = __builtin_amdgcn_mfma_f32_16x16x32_bf16(wl[tt][3], bh1, accV, 0, 0, 0);
            const int o0 = tt ? o0b : o0a;
            float4 bo = tt ? bob : boa;
            float4 uu, vv;
            uu.x = accP[0] - accV[0] + bo.x;  vv.x = accV[0];
            uu.y = accP[1] - accV[1] + bo.y;  vv.y = accV[1];
            uu.z = accP[2] - accV[2] + bo.z;  vv.z = accV[2];
            uu.w = accP[3] - accV[3] + bo.w;  vv.w = accV[3];
            *(float4*)(U + (size_t)(R0 + l15) * NOUT + o0) = uu;
            *(float4*)(V + (size_t)(R0 + l15) * NOUT + o0) = vv;
        }
    }
}

// ---------------------------------------------------------------------------
// knn + aggregate. grid 2048 x 1024 (16 waves), RT=16, 2 blocks/CU
// (32 waves/CU). Phase 1: bf16 MFMA Gram -> fp16 d2 tile (66 KB LDS).
// Phase 2: ONE row per wave: tau via 10-rd ballot radix on fp16>>6
// (granule + 1.0 abs widen, validated r12); scan compaction; fp64 refine
// (4 accumulators); T via 31-rd ballot radix; exact-16 winner mask;
// 16 in-flight V loads. sort128_u64 fallback (>64 survivors or tie).
// ---------------------------------------------------------------------------
__global__ void __launch_bounds__(1024, 2)
knn_k(const float* __restrict__ x,             // [32768][64] fp32 (refine)
      const unsigned short* __restrict__ xb16, // [32768][64] bf16
      const float* __restrict__ sq,
      const float* __restrict__ U,
      const float* __restrict__ V,
      float* __restrict__ out)
{
    extern __shared__ __align__(16) unsigned char smem[];
    unsigned short* d2h = (unsigned short*)smem;   // [RT][HSTR] halves
    __shared__ unsigned short cbuf[16][128];

    // XCD-aware decode: q%8 = XCD; each XCD gets 2 full batches
    const int q   = blockIdx.x;
    const int xcd = q & 7;
    const int k_  = q >> 3;               // 0..255
    const int bb  = xcd * 2 + (k_ >> 7);  // batch
    const int rt  = k_ & 127;             // row tile within batch
    const int R0l = rt * RT;
    const int R0g = bb * NP + R0l;
    const int tid = threadIdx.x;
    const int w   = tid >> 6;             // 0..15
    const int l   = tid & 63;
    const int l15 = l & 15, lg = l >> 4, kc = lg * 8;

    // N-operand fragments: the 16 block rows
    const unsigned short* nr = xb16 + (size_t)(R0g + l15) * ND + kc;
    bf16x8 n0 = *(const bf16x8*)(nr);
    bf16x8 n1 = *(const bf16x8*)(nr + 32);
    const float sqrow = sq[R0g + l15];

    const unsigned short* xbb = xb16 + (size_t)bb * NP * ND;
    const float* sqb = sq + bb * NP;

    // ---- Phase 1: MFMA Gram -> fp16 d2 in LDS (8 col-tiles per wave) ----
#pragma unroll 4
    for (int t = 0; t < 8; ++t) {
        const int cb = (w * 8 + t) * 16;
        const unsigned short* ar = xbb + (size_t)(cb + l15) * ND + kc;
        bf16x8 a0 = *(const bf16x8*)(ar);
        bf16x8 a1 = *(const bf16x8*)(ar + 32);
        f32x4 acc = {0.f, 0.f, 0.f, 0.f};
        acc = __builtin_amdgcn_mfma_f32_16x16x32_bf16(a0, n0, acc, 0, 0, 0);
        acc = __builtin_amdgcn_mfma_f32_16x16x32_bf16(a1, n1, acc, 0, 0, 0);
        // D[batch col][block row]: lane holds block row = l15, cols jb4..jb4+3
        const int jb4 = cb + lg * 4;
        float4 sq4 = *(const float4*)(sqb + jb4);
        unsigned short hh[4];
#pragma unroll
        for (int i = 0; i < 4; ++i) {
            float sqc = (i == 0) ? sq4.x : (i == 1) ? sq4.y : (i == 2) ? sq4.z : sq4.w;
            float d2 = fmaxf(fmaf(-2.f, acc[i], sqrow + sqc), 0.f);
            unsigned short h = __builtin_bit_cast(unsigned short, (_Float16)d2);
            if (R0l + l15 == jb4 + i) h = 0x7C00;   // self -> +inf
            hh[i] = h;
        }
        ushort4 hv; hv.x = hh[0]; hv.y = hh[1]; hv.z = hh[2]; hv.w = hh[3];
        *(ushort4*)(d2h + (size_t)l15 * HSTR + jb4) = hv;
    }
    __syncthreads();

    // ---- Phase 2: ONE row per wave ----
    const int gcbase = bb * NP;
    {
        const int r  = w;
        const int gr = R0g + r;
        const unsigned short* rowp = d2h + (size_t)r * HSTR;

        // load 32 fp16 values; slot (s,i) <-> col j = 256*s + 4*l + i
        unsigned int h[32];
#pragma unroll
        for (int s = 0; s < 8; ++s) {
            ushort4 hv = *(const ushort4*)(rowp + (s * 64 + l) * 4);
            h[s*4+0] = hv.x; h[s*4+1] = hv.y; h[s*4+2] = hv.z; h[s*4+3] = hv.w;
        }
        unsigned int mnh = h[0];
#pragma unroll
        for (int i = 1; i < 32; ++i) mnh = (h[i] < mnh) ? h[i] : mnh;

        // tau: 10-round ballot radix on fp16>>6 (granule-inclusive, r12-validated)
        unsigned int m6 = mnh >> 6;
        unsigned int t6 = 0;
#pragma unroll
        for (int b = 9; b >= 0; --b) {
            unsigned int cand = t6 | (1u << b);
            int c = __popcll(__ballot(m6 < cand));
            if (c < 16) t6 = cand;
        }
        // widen: whole granule + 1.0 absolute (bf16 Gram noise) + 1 ulp
        float tf = (float)__builtin_bit_cast(_Float16, (unsigned short)((t6 << 6) | 0x3F)) + 1.0f;
        unsigned int tauh =
            (unsigned int)__builtin_bit_cast(unsigned short, (_Float16)tf) + 1u;

        // per-lane survivor pack (slot ids, 5 bits each, up to 4)
        unsigned int packed = 0; int cnt = 0;
#pragma unroll
        for (int i = 0; i < 32; ++i) {
            if (h[i] <= tauh) {
                if (cnt < 4) packed |= (unsigned)i << (5 * cnt);
                ++cnt;
            }
        }
        bool ovf = (__ballot(cnt > 4) != 0ull);   // wave-uniform

        cbuf[w][l]      = 0xFFFF;
        cbuf[w][64 + l] = 0xFFFF;
        int total;
        if (!ovf) {
            int inc = cnt;
#pragma unroll
            for (int off = 1; off < 64; off <<= 1) {
                int nv = __shfl_up(inc, off, 64);
                if (l >= off) inc += nv;
            }
            int excl = inc - cnt;
            total = __shfl(inc, 63, 64);
#pragma unroll
            for (int kk = 0; kk < 4; ++kk) {
                if (kk < cnt && excl + kk < 128) {
                    int slot = (packed >> (5 * kk)) & 31;
                    cbuf[w][excl + kk] =
                        (unsigned short)(256 * (slot >> 2) + 4 * l + (slot & 3));
                }
            }
        } else {
            int base = 0;
#pragma unroll 1
            for (int i = 0; i < 32; ++i) {
                bool pred = (h[i] <= tauh);
                unsigned long long m = __ballot(pred);
                int pos = base + lanes_below(m);
                if (pred && pos < 128)
                    cbuf[w][pos] = (unsigned short)(256 * (i >> 2) + 4 * l + (i & 3));
                base += __popcll(m);
            }
            total = base;
        }
        asm volatile("s_waitcnt lgkmcnt(0)" ::: "memory");
        __builtin_amdgcn_sched_barrier(0);

        // hoisted independent U load (overlaps the serial section below)
        float2 uu = *(const float2*)(U + (size_t)gr * NOUT + (l << 1));

        const float* Vb = V + (size_t)bb * NP * NOUT;
        float mv0 = -1e30f, mv1 = -1e30f;
        int jc = cbuf[w][l];

        bool fast = (total <= 64);
        unsigned long long win_m = 0ull;
        if (fast) {
            unsigned int dbits = 0xFFFFFFFFu;
            if (jc != 0xFFFF)
                dbits = __float_as_uint(refine_d(x, gr, gcbase, jc));

            // T = 16th smallest refined value: 31-round ballot radix (0 DS)
            unsigned int T = 0;
#pragma unroll
            for (int b = 30; b >= 0; --b) {
                unsigned int cand = T | (1u << b);
                int c = __popcll(__ballot(dbits < cand));
                if (c < 16) T = cand;
            }
            unsigned long long less_m = __ballot(dbits < T);
            int c_less = __popcll(less_m);
            int need = 16 - c_less;
            unsigned long long tie_m = __ballot(dbits == T);
            if (__popcll(tie_m) == need) {
                win_m = less_m | tie_m;           // exactly 16, unambiguous
            } else {
                fast = false;                      // ambiguous fp32 tie: exact path
            }
        }

        if (fast) {
            int jns[NK];
            unsigned long long mm = win_m;
#pragma unroll
            for (int n = 0; n < NK; ++n) {
                int ln = __ffsll((long long)mm) - 1;
                jns[n] = __builtin_amdgcn_readlane(jc, ln);
                mm &= mm - 1;
            }
            float2 vv[NK];
#pragma unroll
            for (int n = 0; n < NK; ++n)
                vv[n] = *(const float2*)(Vb + (size_t)jns[n] * NOUT + (l << 1));
#pragma unroll
            for (int n = 0; n < NK; ++n) {
                mv0 = fmaxf(mv0, vv[n].x);
                mv1 = fmaxf(mv1, vv[n].y);
            }
        } else {
            // exact fallback: sort refined keys with index tiebreak
            int jc1 = cbuf[w][64 + l];
            unsigned long long rk0 = (jc != 0xFFFF)
                ? ((((unsigned long long)__float_as_uint(refine_d(x, gr, gcbase, jc))) << 11) | (unsigned)jc)
                : ~0ull;
            unsigned long long rk1 = (jc1 != 0xFFFF)
                ? ((((unsigned long long)__float_as_uint(refine_d(x, gr, gcbase, jc1))) << 11) | (unsigned)jc1)
                : ~0ull;
            bitonic_sort128_u64(rk0, rk1, l);
            int nbr = (int)(rk0 & 2047u);
            int jns[NK];
#pragma unroll
            for (int n = 0; n < NK; ++n)
                jns[n] = __builtin_amdgcn_readlane(nbr, n);
            float2 vv[NK];
#pragma unroll
            for (int n = 0; n < NK; ++n)
                vv[n] = *(const float2*)(Vb + (size_t)jns[n] * NOUT + (l << 1));
#pragma unroll
            for (int n = 0; n < NK; ++n) {
                mv0 = fmaxf(mv0, vv[n].x);
                mv1 = fmaxf(mv1, vv[n].y);
            }
        }

        float2 ov;
        ov.x = fmaxf(uu.x + mv0, 0.f);
        ov.y = fmaxf(uu.y + mv1, 0.f);
        *(float2*)(out + (size_t)gr * NOUT + (l << 1)) = ov;
    }
}

extern "C" void kernel_launch(void* const* d_in, const int* in_sizes, int n_in,
                              void* d_out, int out_size, void* d_ws, size_t ws_size,
                              hipStream_t stream) {
    const float* x    = (const float*)d_in[0];   // fp32 [32768][64]
    // d_in[1] = pos (unused), d_in[2] = batch (unused; uniform sorted segments)
    const float* W    = (const float*)d_in[3];   // fp32 [128][128]
    const float* bias = (const float*)d_in[4];   // fp32 [128]
    float* out = (float*)d_out;                  // fp32 [32768][128]

    float* sq = (float*)d_ws;                               // 32768 f32
    float* U  = sq + NBAT * NP;                             // 4.19M f32
    float* V  = U  + (size_t)NBAT * NP * NOUT;              // 4.19M f32
    unsigned short* xb16 = (unsigned short*)(V + (size_t)NBAT * NP * NOUT);

    prep_k<<<512, 256, 0, stream>>>(x, W, bias, sq, U, V, xb16);

    const int lds_bytes = RT * HSTR * 2;                    // 65,664 B
    (void)hipFuncSetAttribute((const void*)knn_k,
                        hipFuncAttributeMaxDynamicSharedMemorySize, lds_bytes);
    knn_k<<<2048, 1024, lds_bytes, stream>>>(x, xb16, sq, U, V, out);
}

// Round 15
// 159.995 us; speedup vs baseline: 1.3758x; 1.0342x over previous
//
#include <hip/hip_runtime.h>

typedef __bf16 bf16x8 __attribute__((ext_vector_type(8)));
typedef float  f32x4  __attribute__((ext_vector_type(4)));

#define NBAT 16
#define NP   2048
#define ND   64
#define NOUT 128
#define NK   16
#define RT   16            // rows per knn block
#define HSTR 2052          // d2 LDS row stride in halves (4104 B, 8B-aligned)

static __device__ __forceinline__ unsigned short f2bf(float f) {
    unsigned u = __float_as_uint(f);
    u += 0x7FFF + ((u >> 16) & 1);      // RNE
    return (unsigned short)(u >> 16);
}
static __device__ __forceinline__ int lanes_below(unsigned long long m) {
    return (int)__builtin_amdgcn_mbcnt_hi((unsigned)(m >> 32),
             __builtin_amdgcn_mbcnt_lo((unsigned)m, 0u));
}
static __device__ __forceinline__ unsigned long long umin64(unsigned long long a, unsigned long long b){ return a < b ? a : b; }
static __device__ __forceinline__ unsigned long long umax64(unsigned long long a, unsigned long long b){ return a < b ? b : a; }

// ascending bitonic sort of 128 u64 keys, element e = slot*64 + lane (rare path)
static __device__ __forceinline__ void bitonic_sort128_u64(unsigned long long &k0,
                                                           unsigned long long &k1, int lane) {
#pragma unroll
    for (int k = 2; k <= 64; k <<= 1) {
#pragma unroll
        for (int j = k >> 1; j >= 1; j >>= 1) {
            bool lower = ((lane & j) == 0);
            bool up0 = (k == 64) ? true  : ((lane & k) == 0);
            bool up1 = (k == 64) ? false : ((lane & k) == 0);
            unsigned long long o0 = __shfl_xor(k0, j, 64);
            k0 = (up0 == lower) ? umin64(k0, o0) : umax64(k0, o0);
            unsigned long long o1 = __shfl_xor(k1, j, 64);
            k1 = (up1 == lower) ? umin64(k1, o1) : umax64(k1, o1);
        }
    }
    { unsigned long long mn = umin64(k0, k1), mx = umax64(k0, k1); k0 = mn; k1 = mx; }
#pragma unroll
    for (int j = 32; j >= 1; j >>= 1) {
        bool lower = ((lane & j) == 0);
        unsigned long long o0 = __shfl_xor(k0, j, 64);
        k0 = lower ? umin64(k0, o0) : umax64(k0, o0);
        unsigned long long o1 = __shfl_xor(k1, j, 64);
        k1 = lower ? umin64(k1, o1) : umax64(k1, o1);
    }
}

// fp64-exact squared distance, rounded to fp32
static __device__ __forceinline__ float
refine_d(const float* __restrict__ x, int gr, int gcbase, int jc) {
    const float* xr = x + (size_t)gr * ND;
    const float* xc = x + (size_t)(gcbase + jc) * ND;
    double s0 = 0.0, s1 = 0.0;
#pragma unroll
    for (int k8 = 0; k8 < 8; ++k8) {
        float4 a  = *(const float4*)(xr + k8 * 8);
        float4 b  = *(const float4*)(xc + k8 * 8);
        float4 a2 = *(const float4*)(xr + k8 * 8 + 4);
        float4 b2 = *(const float4*)(xc + k8 * 8 + 4);
        double e0 = (double)a.x - (double)b.x;
        double e1 = (double)a.y - (double)b.y;
        double e2 = (double)a.z - (double)b.z;
        double e3 = (double)a.w - (double)b.w;
        s0 = fma(e0, e0, s0); s0 = fma(e1, e1, s0);
        s0 = fma(e2, e2, s0); s0 = fma(e3, e3, s0);
        double f0 = (double)a2.x - (double)b2.x;
        double f1 = (double)a2.y - (double)b2.y;
        double f2 = (double)a2.z - (double)b2.z;
        double f3 = (double)a2.w - (double)b2.w;
        s1 = fma(f0, f0, s1); s1 = fma(f1, f1, s1);
        s1 = fma(f2, f2, s1); s1 = fma(f3, f3, s1);
    }
    return (float)(s0 + s1);
}

// split fp32 x8 -> hi/lo bf16x8 (hi = RNE(f); lo = RNE(f - hi))
static __device__ __forceinline__ void cvt_hilo(const float* __restrict__ p,
                                                bf16x8 &hi, bf16x8 &lo) {
    float4 a = *(const float4*)p, b = *(const float4*)(p + 4);
    float f[8] = {a.x, a.y, a.z, a.w, b.x, b.y, b.z, b.w};
#pragma unroll
    for (int i = 0; i < 8; ++i) {
        __bf16 h = (__bf16)f[i];
        hi[i] = h;
        lo[i] = (__bf16)(f[i] - (float)h);
    }
}

// ---------------------------------------------------------------------------
// prep (LDS-free, MFMA): sq (fp64-acc), xb16 (bf16 copy), U=(W1-W2)x+b, V=W2x.
// grid 512 x 256; each block 4 row-tiles of 16; W frags hoisted across tiles.
// ---------------------------------------------------------------------------
__global__ void __launch_bounds__(256)
prep_k(const float* __restrict__ x,     // [32768][64]
       const float* __restrict__ W,     // [128][128] (cols 0..63 = W1, 64..127 = W2)
       const float* __restrict__ bias,  // [128]
       float* __restrict__ sq, float* __restrict__ U,
       float* __restrict__ V,  unsigned short* __restrict__ xb16)
{
    const int blk = blockIdx.x, tid = threadIdx.x;
    const int R0b = blk * 64;
    const int w  = tid >> 6, l = tid & 63;
    const int l15 = l & 15, lg = l >> 4, kc = lg * 8;

    bf16x8 wh[2][4], wl[2][4];
#pragma unroll
    for (int tt = 0; tt < 2; ++tt) {
        const float* wb = W + (size_t)((w + tt * 4) * 16 + l15) * (2 * ND) + kc;
#pragma unroll
        for (int p = 0; p < 4; ++p)
            cvt_hilo(wb + p * 32, wh[tt][p], wl[tt][p]);
    }
    const int o0a = w * 16 + lg * 4;
    const int o0b = (w + 4) * 16 + lg * 4;
    float4 boa = *(const float4*)(bias + o0a);
    float4 bob = *(const float4*)(bias + o0b);

#pragma unroll 1
    for (int s4 = 0; s4 < 4; ++s4) {
        const int R0 = R0b + s4 * 16;
        {
            int r = tid >> 4, c = (tid & 15) * 4;
            float4 v = *(const float4*)(x + (size_t)(R0 + r) * ND + c);
            ushort4 hb;
            hb.x = f2bf(v.x); hb.y = f2bf(v.y); hb.z = f2bf(v.z); hb.w = f2bf(v.w);
            *(ushort4*)(xb16 + (size_t)(R0 + r) * ND + c) = hb;
        }
        if (tid < 128) {
            int r = tid >> 3, seg = tid & 7;
            const float* p = x + (size_t)(R0 + r) * ND + seg * 8;
            float4 a = *(const float4*)(p);
            float4 b = *(const float4*)(p + 4);
            double s = (double)a.x * a.x + (double)a.y * a.y +
                       (double)a.z * a.z + (double)a.w * a.w +
                       (double)b.x * b.x + (double)b.y * b.y +
                       (double)b.z * b.z + (double)b.w * b.w;
            s += __shfl_xor(s, 1, 64);
            s += __shfl_xor(s, 2, 64);
            s += __shfl_xor(s, 4, 64);
            if (seg == 0) sq[R0 + r] = (float)s;
        }
        const float* xr = x + (size_t)(R0 + l15) * ND + kc;
        bf16x8 bh0, bl0, bh1, bl1;
        cvt_hilo(xr,      bh0, bl0);
        cvt_hilo(xr + 32, bh1, bl1);
#pragma unroll
        for (int tt = 0; tt < 2; ++tt) {
            f32x4 accP = {0.f, 0.f, 0.f, 0.f};
            f32x4 accV = {0.f, 0.f, 0.f, 0.f};
            accP = __builtin_amdgcn_mfma_f32_16x16x32_bf16(wh[tt][0], bh0, accP, 0, 0, 0);
            accP = __builtin_amdgcn_mfma_f32_16x16x32_bf16(wh[tt][0], bl0, accP, 0, 0, 0);
            accP = __builtin_amdgcn_mfma_f32_16x16x32_bf16(wl[tt][0], bh0, accP, 0, 0, 0);
            accP = __builtin_amdgcn_mfma_f32_16x16x32_bf16(wh[tt][1], bh1, accP, 0, 0, 0);
            accP = __builtin_amdgcn_mfma_f32_16x16x32_bf16(wh[tt][1], bl1, accP, 0, 0, 0);
            accP = __builtin_amdgcn_mfma_f32_16x16x32_bf16(wl[tt][1], bh1, accP, 0, 0, 0);
            accV = __builtin_amdgcn_mfma_f32_16x16x32_bf16(wh[tt][2], bh0, accV, 0, 0, 0);
            accV = __builtin_amdgcn_mfma_f32_16x16x32_bf16(wh[tt][2], bl0, accV, 0, 0, 0);
            accV = __builtin_amdgcn_mfma_f32_16x16x32_bf16(wl[tt][2], bh0, accV, 0, 0, 0);
            accV = __builtin_amdgcn_mfma_f32_16x16x32_bf16(wh[tt][3], bh1, accV, 0, 0, 0);
            accV = __builtin_amdgcn_mfma_f32_16x16x32_bf16(wh[tt][3], bl1, accV, 0, 0, 0);
            accV = __builtin_amdgcn_mfma_f32_16x16x32_bf16(wl[tt][3], bh1, accV, 0, 0, 0);
            const int o0 = tt ? o0b : o0a;
            float4 bo = tt ? bob : boa;
            float4 uu, vv;
            uu.x = accP[0] - accV[0] + bo.x;  vv.x = accV[0];
            uu.y = accP[1] - accV[1] + bo.y;  vv.y = accV[1];
            uu.z = accP[2] - accV[2] + bo.z;  vv.z = accV[2];
            uu.w = accP[3] - accV[3] + bo.w;  vv.w = accV[3];
            *(float4*)(U + (size_t)(R0 + l15) * NOUT + o0) = uu;
            *(float4*)(V + (size_t)(R0 + l15) * NOUT + o0) = vv;
        }
    }
}

// ---------------------------------------------------------------------------
// knn + aggregate. grid 2048 x 1024 (16 waves), RT=16, 2 blocks/CU
// (32 waves/CU). Phase 1: bf16 MFMA Gram -> fp16 d2 tile (66 KB LDS).
// Phase 2: ONE row per wave. r11 base; ONLY change: both ballot-radix
// selects use 2-bit digits (3 independent ballots/round) -> tau 8 rounds,
// T 16 rounds. Selected values are bit-identical to single-bit radix.
// ---------------------------------------------------------------------------
__global__ void __launch_bounds__(1024, 2)
knn_k(const float* __restrict__ x,             // [32768][64] fp32 (refine)
      const unsigned short* __restrict__ xb16, // [32768][64] bf16
      const float* __restrict__ sq,
      const float* __restrict__ U,
      const float* __restrict__ V,
      float* __restrict__ out)
{
    extern __shared__ __align__(16) unsigned char smem[];
    unsigned short* d2h = (unsigned short*)smem;   // [RT][HSTR] halves
    __shared__ unsigned short cbuf[16][128];

    // XCD-aware decode: q%8 = XCD; each XCD gets 2 full batches
    const int q   = blockIdx.x;
    const int xcd = q & 7;
    const int k_  = q >> 3;               // 0..255
    const int bb  = xcd * 2 + (k_ >> 7);  // batch
    const int rt  = k_ & 127;             // row tile within batch
    const int R0l = rt * RT;
    const int R0g = bb * NP + R0l;
    const int tid = threadIdx.x;
    const int w   = tid >> 6;             // 0..15
    const int l   = tid & 63;
    const int l15 = l & 15, lg = l >> 4, kc = lg * 8;

    // N-operand fragments: the 16 block rows
    const unsigned short* nr = xb16 + (size_t)(R0g + l15) * ND + kc;
    bf16x8 n0 = *(const bf16x8*)(nr);
    bf16x8 n1 = *(const bf16x8*)(nr + 32);
    const float sqrow = sq[R0g + l15];

    const unsigned short* xbb = xb16 + (size_t)bb * NP * ND;
    const float* sqb = sq + bb * NP;

    // ---- Phase 1: MFMA Gram -> fp16 d2 in LDS (8 col-tiles per wave) ----
#pragma unroll 4
    for (int t = 0; t < 8; ++t) {
        const int cb = (w * 8 + t) * 16;
        const unsigned short* ar = xbb + (size_t)(cb + l15) * ND + kc;
        bf16x8 a0 = *(const bf16x8*)(ar);
        bf16x8 a1 = *(const bf16x8*)(ar + 32);
        f32x4 acc = {0.f, 0.f, 0.f, 0.f};
        acc = __builtin_amdgcn_mfma_f32_16x16x32_bf16(a0, n0, acc, 0, 0, 0);
        acc = __builtin_amdgcn_mfma_f32_16x16x32_bf16(a1, n1, acc, 0, 0, 0);
        // D[batch col][block row]: lane holds block row = l15, cols jb4..jb4+3
        const int jb4 = cb + lg * 4;
        float4 sq4 = *(const float4*)(sqb + jb4);
        unsigned short hh[4];
#pragma unroll
        for (int i = 0; i < 4; ++i) {
            float sqc = (i == 0) ? sq4.x : (i == 1) ? sq4.y : (i == 2) ? sq4.z : sq4.w;
            float d2 = fmaxf(fmaf(-2.f, acc[i], sqrow + sqc), 0.f);
            unsigned short h = __builtin_bit_cast(unsigned short, (_Float16)d2);
            if (R0l + l15 == jb4 + i) h = 0x7C00;   // self -> +inf
            hh[i] = h;
        }
        ushort4 hv; hv.x = hh[0]; hv.y = hh[1]; hv.z = hh[2]; hv.w = hh[3];
        *(ushort4*)(d2h + (size_t)l15 * HSTR + jb4) = hv;
    }
    __syncthreads();

    // ---- Phase 2: ONE row per wave ----
    const int gcbase = bb * NP;
    {
        const int r  = w;
        const int gr = R0g + r;
        const unsigned short* rowp = d2h + (size_t)r * HSTR;

        // load 32 fp16 values; slot (s,i) <-> col j = 256*s + 4*l + i
        unsigned int h[32];
#pragma unroll
        for (int s = 0; s < 8; ++s) {
            ushort4 hv = *(const ushort4*)(rowp + (s * 64 + l) * 4);
            h[s*4+0] = hv.x; h[s*4+1] = hv.y; h[s*4+2] = hv.z; h[s*4+3] = hv.w;
        }
        unsigned int mnh = h[0];
#pragma unroll
        for (int i = 1; i < 32; ++i) mnh = (h[i] < mnh) ? h[i] : mnh;

        // tau = 16th smallest of the 64 lane-minima: 2-bit-digit ballot radix
        // (8 rounds x 3 independent ballots; result identical to 16 1-bit rds)
        unsigned int t16 = 0;
#pragma unroll
        for (int b = 14; b >= 0; b -= 2) {
            unsigned int c1 = t16 | (1u << b);
            unsigned int c2 = t16 | (2u << b);
            unsigned int c3 = t16 | (3u << b);
            int n1 = __popcll(__ballot(mnh < c1));
            int n2 = __popcll(__ballot(mnh < c2));
            int n3 = __popcll(__ballot(mnh < c3));
            if (n3 < 16)      t16 = c3;
            else if (n2 < 16) t16 = c2;
            else if (n1 < 16) t16 = c1;
        }
        // widen by +1.0 ABSOLUTE (bf16 Gram noise, 11 sigma) + 1 ulp
        float tf = (float)__builtin_bit_cast(_Float16, (unsigned short)t16) + 1.0f;
        unsigned int tauh =
            (unsigned int)__builtin_bit_cast(unsigned short, (_Float16)tf) + 1u;

        // per-lane survivor pack (slot ids, 5 bits each, up to 4)
        unsigned int packed = 0; int cnt = 0;
#pragma unroll
        for (int i = 0; i < 32; ++i) {
            if (h[i] <= tauh) {
                if (cnt < 4) packed |= (unsigned)i << (5 * cnt);
                ++cnt;
            }
        }
        bool ovf = (__ballot(cnt > 4) != 0ull);   // wave-uniform

        cbuf[w][l]      = 0xFFFF;
        cbuf[w][64 + l] = 0xFFFF;
        int total;
        if (!ovf) {
            int inc = cnt;
#pragma unroll
            for (int off = 1; off < 64; off <<= 1) {
                int nv = __shfl_up(inc, off, 64);
                if (l >= off) inc += nv;
            }
            int excl = inc - cnt;
            total = __shfl(inc, 63, 64);
#pragma unroll
            for (int kk = 0; kk < 4; ++kk) {
                if (kk < cnt && excl + kk < 128) {
                    int slot = (packed >> (5 * kk)) & 31;
                    cbuf[w][excl + kk] =
                        (unsigned short)(256 * (slot >> 2) + 4 * l + (slot & 3));
                }
            }
        } else {
            int base = 0;
#pragma unroll 1
            for (int i = 0; i < 32; ++i) {
                bool pred = (h[i] <= tauh);
                unsigned long long m = __ballot(pred);
                int pos = base + lanes_below(m);
                if (pred && pos < 128)
                    cbuf[w][pos] = (unsigned short)(256 * (i >> 2) + 4 * l + (i & 3));
                base += __popcll(m);
            }
            total = base;
        }
        asm volatile("s_waitcnt lgkmcnt(0)" ::: "memory");
        __builtin_amdgcn_sched_barrier(0);

        const float* Vb = V + (size_t)bb * NP * NOUT;
        float mv0 = -1e30f, mv1 = -1e30f;
        int jc = cbuf[w][l];

        bool fast = (total <= 64);
        unsigned long long win_m = 0ull;
        if (fast) {
            unsigned int dbits = 0xFFFFFFFFu;
            if (jc != 0xFFFF)
                dbits = __float_as_uint(refine_d(x, gr, gcbase, jc));

            // T = 16th smallest refined value: 2-bit-digit radix over 32 bits
            // (16 rounds x 3 independent ballots; invalid=0xFFFFFFFF keeps
            //  the top digit at 0 since >=16 valid values exist)
            unsigned int T = 0;
#pragma unroll
            for (int b = 30; b >= 0; b -= 2) {
                unsigned int c1 = T | (1u << b);
                unsigned int c2 = T | (2u << b);
                unsigned int c3 = T | (3u << b);
                int n1 = __popcll(__ballot(dbits < c1));
                int n2 = __popcll(__ballot(dbits < c2));
                int n3 = __popcll(__ballot(dbits < c3));
                if (n3 < 16)      T = c3;
                else if (n2 < 16) T = c2;
                else if (n1 < 16) T = c1;
            }
            unsigned long long less_m = __ballot(dbits < T);
            int c_less = __popcll(less_m);
            int need = 16 - c_less;
            unsigned long long tie_m = __ballot(dbits == T);
            if (__popcll(tie_m) == need) {
                win_m = less_m | tie_m;           // exactly 16, unambiguous
            } else {
                fast = false;                      // ambiguous fp32 tie: exact path
            }
        }

        if (fast) {
            int jns[NK];
            unsigned long long mm = win_m;
#pragma unroll
            for (int n = 0; n < NK; ++n) {
                int ln = __ffsll((long long)mm) - 1;
                jns[n] = __builtin_amdgcn_readlane(jc, ln);
                mm &= mm - 1;
            }
            float2 vv[NK];
#pragma unroll
            for (int n = 0; n < NK; ++n)
                vv[n] = *(const float2*)(Vb + (size_t)jns[n] * NOUT + (l << 1));
#pragma unroll
            for (int n = 0; n < NK; ++n) {
                mv0 = fmaxf(mv0, vv[n].x);
                mv1 = fmaxf(mv1, vv[n].y);
            }
        } else {
            // exact fallback: sort refined keys with index tiebreak
            int jc1 = cbuf[w][64 + l];
            unsigned long long rk0 = (jc != 0xFFFF)
                ? ((((unsigned long long)__float_as_uint(refine_d(x, gr, gcbase, jc))) << 11) | (unsigned)jc)
                : ~0ull;
            unsigned long long rk1 = (jc1 != 0xFFFF)
                ? ((((unsigned long long)__float_as_uint(refine_d(x, gr, gcbase, jc1))) << 11) | (unsigned)jc1)
                : ~0ull;
            bitonic_sort128_u64(rk0, rk1, l);
            int nbr = (int)(rk0 & 2047u);
            int jns[NK];
#pragma unroll
            for (int n = 0; n < NK; ++n)
                jns[n] = __builtin_amdgcn_readlane(nbr, n);
            float2 vv[NK];
#pragma unroll
            for (int n = 0; n < NK; ++n)
                vv[n] = *(const float2*)(Vb + (size_t)jns[n] * NOUT + (l << 1));
#pragma unroll
            for (int n = 0; n < NK; ++n) {
                mv0 = fmaxf(mv0, vv[n].x);
                mv1 = fmaxf(mv1, vv[n].y);
            }
        }

        float2 uu = *(const float2*)(U + (size_t)gr * NOUT + (l << 1));
        float2 ov;
        ov.x = fmaxf(uu.x + mv0, 0.f);
        ov.y = fmaxf(uu.y + mv1, 0.f);
        *(float2*)(out + (size_t)gr * NOUT + (l << 1)) = ov;
    }
}

extern "C" void kernel_launch(void* const* d_in, const int* in_sizes, int n_in,
                              void* d_out, int out_size, void* d_ws, size_t ws_size,
                              hipStream_t stream) {
    const float* x    = (const float*)d_in[0];   // fp32 [32768][64]
    // d_in[1] = pos (unused), d_in[2] = batch (unused; uniform sorted segments)
    const float* W    = (const float*)d_in[3];   // fp32 [128][128]
    const float* bias = (const float*)d_in[4];   // fp32 [128]
    float* out = (float*)d_out;                  // fp32 [32768][128]

    float* sq = (float*)d_ws;                               // 32768 f32
    float* U  = sq + NBAT * NP;                             // 4.19M f32
    float* V  = U  + (size_t)NBAT * NP * NOUT;              // 4.19M f32
    unsigned short* xb16 = (unsigned short*)(V + (size_t)NBAT * NP * NOUT);

    prep_k<<<512, 256, 0, stream>>>(x, W, bias, sq, U, V, xb16);

    const int lds_bytes = RT * HSTR * 2;                    // 65,664 B
    (void)hipFuncSetAttribute((const void*)knn_k,
                        hipFuncAttributeMaxDynamicSharedMemorySize, lds_bytes);
    knn_k<<<2048, 1024, lds_bytes, stream>>>(x, xb16, sq, U, V, out);
}